// Round 1
// baseline (1995.623 us; speedup 1.0000x reference)
//
#include <hip/hip_runtime.h>
#include <math.h>

// SPD normalization, eigh-free: Chebyshev-PS logm + Newton-Schulz sqrt/invsqrt.
// All matrices 64x64 fp32. B=8192.

#define NPAD 68                 // LDS row stride in floats (272B, 16B-aligned)
#define SLOT (64 * NPAD)

struct ChebArgs {
  float g[10][8];               // folded Chebyshev-PS coefficients (r=10 blocks, s=8)
  float mhat, invh;             // U = (M - mhat*I) * invh
};

// ---------------- device helpers ----------------

__device__ __forceinline__ void load_mat(const float* __restrict__ g, float* __restrict__ S) {
#pragma unroll
  for (int q = 0; q < 4; ++q) {
    int idx = threadIdx.x + (q << 8);
    float4 v = reinterpret_cast<const float4*>(g)[idx];
    int row = idx >> 4, c4 = (idx & 15) << 2;
    *reinterpret_cast<float4*>(S + row * NPAD + c4) = v;
  }
}

__device__ __forceinline__ void load_mat_scaled(const float* __restrict__ g, float* __restrict__ S, float sc) {
#pragma unroll
  for (int q = 0; q < 4; ++q) {
    int idx = threadIdx.x + (q << 8);
    float4 v = reinterpret_cast<const float4*>(g)[idx];
    int row = idx >> 4, c4 = (idx & 15) << 2;
    v.x *= sc; v.y *= sc; v.z *= sc; v.w *= sc;
    *reinterpret_cast<float4*>(S + row * NPAD + c4) = v;
  }
}

__device__ __forceinline__ void store_mat_scaled(float* __restrict__ g, const float* __restrict__ S, float sc) {
#pragma unroll
  for (int q = 0; q < 4; ++q) {
    int idx = threadIdx.x + (q << 8);
    int row = idx >> 4, c4 = (idx & 15) << 2;
    float4 v = *reinterpret_cast<const float4*>(S + row * NPAD + c4);
    v.x *= sc; v.y *= sc; v.z *= sc; v.w *= sc;
    reinterpret_cast<float4*>(g)[idx] = v;
  }
}

// C[r][c] = sum_k A[k][r]*B[k][c]  (A must be symmetric => equals (A*B)[r][c]).
// Per-thread 4x4 tile at (ty4, tx4).
__device__ __forceinline__ void gemm64(const float* __restrict__ A, const float* __restrict__ B,
                                       float (&acc)[4][4]) {
  const int tx4 = (threadIdx.x & 15) << 2;
  const int ty4 = (threadIdx.x >> 4) << 2;
#pragma unroll
  for (int i = 0; i < 4; ++i)
#pragma unroll
    for (int j = 0; j < 4; ++j) acc[i][j] = 0.f;
#pragma unroll 4
  for (int k = 0; k < 64; ++k) {
    float4 av = *reinterpret_cast<const float4*>(A + k * NPAD + ty4);
    float4 bv = *reinterpret_cast<const float4*>(B + k * NPAD + tx4);
    float aa[4] = {av.x, av.y, av.z, av.w};
    float bb[4] = {bv.x, bv.y, bv.z, bv.w};
#pragma unroll
    for (int i = 0; i < 4; ++i)
#pragma unroll
      for (int j = 0; j < 4; ++j)
        acc[i][j] = fmaf(aa[i], bb[j], acc[i][j]);
  }
}

__device__ __forceinline__ void store_tile(float* __restrict__ S, const float (&t)[4][4]) {
  const int tx4 = (threadIdx.x & 15) << 2;
  const int ty4 = (threadIdx.x >> 4) << 2;
#pragma unroll
  for (int i = 0; i < 4; ++i)
    *reinterpret_cast<float4*>(S + (ty4 + i) * NPAD + tx4) =
        make_float4(t[i][0], t[i][1], t[i][2], t[i][3]);
}

__device__ __forceinline__ void store_tile_T(float* __restrict__ S, const float (&t)[4][4]) {
  const int tx4 = (threadIdx.x & 15) << 2;
  const int ty4 = (threadIdx.x >> 4) << 2;
#pragma unroll
  for (int i = 0; i < 4; ++i)
#pragma unroll
    for (int j = 0; j < 4; ++j)
      S[(tx4 + j) * NPAD + (ty4 + i)] = t[i][j];
}

__device__ __forceinline__ float block_reduce_sum(float v, float* red) {
  int t = threadIdx.x;
  red[t] = v;
  __syncthreads();
#pragma unroll
  for (int sft = 128; sft >= 1; sft >>= 1) {
    if (t < sft) red[t] += red[t + sft];
    __syncthreads();
  }
  float r = red[0];
  __syncthreads();
  return r;
}

// Coupled Newton-Schulz: A in SY on entry. On exit SY=(A/c)^{1/2}, SZ=(A/c)^{-1/2}.
// Returns c = tr/64 + ||A - (tr/64) I||_F  (>= lambda_max, guarantees convergence).
__device__ float ns_sqrt(float* SY, float* SZ, float* ST, float* red, int iters) {
  const int tx4 = (threadIdx.x & 15) << 2;
  const int ty4 = (threadIdx.x >> 4) << 2;
  float loc = 0.f;
#pragma unroll
  for (int i = 0; i < 4; ++i)
#pragma unroll
    for (int j = 0; j < 4; ++j)
      if (ty4 + i == tx4 + j) loc += SY[(ty4 + i) * NPAD + tx4 + j];
  float m = block_reduce_sum(loc, red) * (1.f / 64.f);
  loc = 0.f;
#pragma unroll
  for (int i = 0; i < 4; ++i)
#pragma unroll
    for (int j = 0; j < 4; ++j) {
      float v = SY[(ty4 + i) * NPAD + tx4 + j] - ((ty4 + i == tx4 + j) ? m : 0.f);
      loc = fmaf(v, v, loc);
    }
  float f = sqrtf(block_reduce_sum(loc, red));
  float c = m + f;
  float rc = 1.f / c;
#pragma unroll
  for (int i = 0; i < 4; ++i)
#pragma unroll
    for (int j = 0; j < 4; ++j) {
      SY[(ty4 + i) * NPAD + tx4 + j] *= rc;
      SZ[(ty4 + i) * NPAD + tx4 + j] = (ty4 + i == tx4 + j) ? 1.f : 0.f;
    }
  __syncthreads();
  for (int it = 0; it < iters; ++it) {
    float acc[4][4];
    gemm64(SZ, SY, acc);                       // Z*Y
    float tm[4][4];
#pragma unroll
    for (int i = 0; i < 4; ++i)
#pragma unroll
      for (int j = 0; j < 4; ++j)
        tm[i][j] = ((ty4 + i == tx4 + j) ? 1.5f : 0.f) - 0.5f * acc[i][j];
    store_tile(ST, tm);
    __syncthreads();
    float ny[4][4], nz[4][4];
    gemm64(SY, ST, ny);                        // Y*T
    gemm64(ST, SZ, nz);                        // T*Z
    __syncthreads();
    store_tile(SY, ny);
    store_tile(SZ, nz);
    __syncthreads();
  }
  return c;
}

// Q_j(U) = g[j][0]*I + sum_{t=1..7} g[j][t]*T_t  (all thread-local registers)
__device__ __forceinline__ void computeQ(const ChebArgs& ca, const float (&T)[7][4][4],
                                         int jj, int ty4, int tx4, float (&dst)[4][4]) {
#pragma unroll
  for (int i = 0; i < 4; ++i)
#pragma unroll
    for (int j = 0; j < 4; ++j) {
      float q = ((ty4 + i) == (tx4 + j)) ? ca.g[jj][0] : 0.f;
#pragma unroll
      for (int t = 1; t <= 7; ++t) q = fmaf(ca.g[jj][t], T[t - 1][i][j], q);
      dst[i][j] = q;
    }
}

// ---------------- kernels ----------------

// Partial batch mean: 512 blocks x 256 thr, 16 batches each -> part[blk][4096]
__global__ void k_mean_part(const float* __restrict__ x, float* __restrict__ part) {
  float4 s[4];
#pragma unroll
  for (int q = 0; q < 4; ++q) s[q] = make_float4(0.f, 0.f, 0.f, 0.f);
  int base = blockIdx.x * 16;
  for (int b = 0; b < 16; ++b) {
    const float4* x4 = reinterpret_cast<const float4*>(x + (size_t)(base + b) * 4096);
#pragma unroll
    for (int q = 0; q < 4; ++q) {
      float4 v = x4[threadIdx.x + (q << 8)];
      s[q].x += v.x; s[q].y += v.y; s[q].z += v.z; s[q].w += v.w;
    }
  }
  float4* p4 = reinterpret_cast<float4*>(part + (size_t)blockIdx.x * 4096);
#pragma unroll
  for (int q = 0; q < 4; ++q) p4[threadIdx.x + (q << 8)] = s[q];
}

// Reduce np partials (stride 4096) -> o[j] = scale * sum_p part[p][j]; grid 16x256
__global__ void k_reduce(const float* __restrict__ part, int np, float scale,
                         float* __restrict__ o) {
  int j = blockIdx.x * 256 + threadIdx.x;
  float s = 0.f;
  for (int p = 0; p < np; ++p) s += part[(size_t)p * 4096 + j];
  o[j] = s * scale;
}

// Block 0: s=sqrtm(mean0), si=invsqrtm(mean0). Block 1: gsq=sqrtm(G).
__global__ __launch_bounds__(256) void k_prep1(const float* __restrict__ mean0,
                                               const float* __restrict__ G,
                                               float* __restrict__ s_out,
                                               float* __restrict__ si_out,
                                               float* __restrict__ gsq_out) {
  __shared__ float SY[SLOT], SZ[SLOT], ST[SLOT];
  __shared__ float red[256];
  if (blockIdx.x == 0) {
    load_mat(mean0, SY);
    __syncthreads();
    float c = ns_sqrt(SY, SZ, ST, red, 9);
    float sc = sqrtf(c);
    store_mat_scaled(s_out, SY, sc);
    store_mat_scaled(si_out, SZ, 1.f / sc);
  } else {
    load_mat(G, SY);
    __syncthreads();
    float c = ns_sqrt(SY, SZ, ST, red, 16);
    store_mat_scaled(gsq_out, SY, sqrtf(c));
  }
}

// Heavy kernel: per matrix, M = si*x*si; U=(M-m)/h; logm(M)=Chebyshev-PS(U);
// accumulate sum over 16 matrices -> part[blk][4096]. 512 blocks x 256 thr.
__global__ __launch_bounds__(256, 2) void k_logm_sum(const float* __restrict__ x,
                                                     const float* __restrict__ si,
                                                     float* __restrict__ part,
                                                     ChebArgs ca) {
  __shared__ float SU[SLOT], SV[SLOT], SS[SLOT];
  const int tx4 = (threadIdx.x & 15) << 2;
  const int ty4 = (threadIdx.x >> 4) << 2;
  float sumT[4][4];
#pragma unroll
  for (int i = 0; i < 4; ++i)
#pragma unroll
    for (int j = 0; j < 4; ++j) sumT[i][j] = 0.f;

  float T[7][4][4];          // T1..T7 (Chebyshev polys of U), registers
  float acc[4][4];

  for (int mm = 0; mm < 16; ++mm) {
    const float* xb = x + ((size_t)blockIdx.x * 16 + mm) * 4096;
    load_mat(si, SU);
    load_mat(xb, SS);
    __syncthreads();
    gemm64(SS, SU, acc);                 // t1 = x*si   (x symmetric)
    __syncthreads();
    store_tile(SS, acc);                 // SS = t1
    __syncthreads();
    gemm64(SU, SS, acc);                 // M = si*t1   (si symmetric)
    // U = (M - mhat I) * invh  -> T1
#pragma unroll
    for (int i = 0; i < 4; ++i)
#pragma unroll
      for (int j = 0; j < 4; ++j)
        T[0][i][j] = (acc[i][j] - ((ty4 + i == tx4 + j) ? ca.mhat : 0.f)) * ca.invh;
    __syncthreads();
    store_tile(SU, T[0]);                // SU = U (si dead)
    __syncthreads();
    gemm64(SU, SU, acc);                 // U*U
#pragma unroll
    for (int i = 0; i < 4; ++i)
#pragma unroll
      for (int j = 0; j < 4; ++j)
        T[1][i][j] = 2.f * acc[i][j] - ((ty4 + i == tx4 + j) ? 1.f : 0.f);
    // T3..T7
#pragma unroll
    for (int n = 3; n <= 7; ++n) {
      __syncthreads();
      store_tile(SS, T[n - 2]);
      __syncthreads();
      gemm64(SU, SS, acc);
#pragma unroll
      for (int i = 0; i < 4; ++i)
#pragma unroll
        for (int j = 0; j < 4; ++j)
          T[n - 1][i][j] = 2.f * acc[i][j] - T[n - 3][i][j];
    }
    // T8 = V -> SV
    __syncthreads();
    store_tile(SS, T[6]);
    __syncthreads();
    gemm64(SU, SS, acc);
    {
      float t8[4][4];
#pragma unroll
      for (int i = 0; i < 4; ++i)
#pragma unroll
        for (int j = 0; j < 4; ++j) t8[i][j] = 2.f * acc[i][j] - T[5][i][j];
      store_tile(SV, t8);
    }
    // Clenshaw in V over 10 blocks: b9=Q9; b_j = Q_j + 2V b_{j+1} - b_{j+2}
    float bcur[4][4], bprev[4][4];
    computeQ(ca, T, 9, ty4, tx4, bcur);
#pragma unroll
    for (int i = 0; i < 4; ++i)
#pragma unroll
      for (int j = 0; j < 4; ++j) bprev[i][j] = 0.f;
#pragma unroll
    for (int jj = 8; jj >= 1; --jj) {
      __syncthreads();
      store_tile(SS, bcur);
      __syncthreads();
      gemm64(SV, SS, acc);               // V*b_{j+1}
      float bn[4][4];
      computeQ(ca, T, jj, ty4, tx4, bn);
#pragma unroll
      for (int i = 0; i < 4; ++i)
#pragma unroll
        for (int j = 0; j < 4; ++j) {
          bn[i][j] = bn[i][j] + 2.f * acc[i][j] - bprev[i][j];
          bprev[i][j] = bcur[i][j];
          bcur[i][j] = bn[i][j];
        }
    }
    __syncthreads();
    store_tile(SS, bcur);
    __syncthreads();
    gemm64(SV, SS, acc);                 // V*b_1
    {
      float q0[4][4];
      computeQ(ca, T, 0, ty4, tx4, q0);
#pragma unroll
      for (int i = 0; i < 4; ++i)
#pragma unroll
        for (int j = 0; j < 4; ++j)
          sumT[i][j] += q0[i][j] + acc[i][j] - bprev[i][j];
    }
    __syncthreads();                     // before next mm overwrites SU/SS
  }
  float* pb = part + (size_t)blockIdx.x * 4096;
#pragma unroll
  for (int i = 0; i < 4; ++i)
    *reinterpret_cast<float4*>(pb + (ty4 + i) * 64 + tx4) =
        make_float4(sumT[i][0], sumT[i][1], sumT[i][2], sumT[i][3]);
}

// E=expm(meanT); center=s*E*s; csi=invsqrtm(center); PT=(gsq*csi)^T. One block.
__global__ __launch_bounds__(256) void k_prep2(const float* __restrict__ meanT,
                                               const float* __restrict__ s,
                                               const float* __restrict__ gsq,
                                               float* __restrict__ PT) {
  __shared__ float SY[SLOT], SZ[SLOT], ST[SLOT];
  __shared__ float red[256];
  const int tx4 = (threadIdx.x & 15) << 2;
  const int ty4 = (threadIdx.x >> 4) << 2;
  float acc[4][4];
  // A' = meanT/8 -> SZ ; B = I -> SY
  load_mat_scaled(meanT, SZ, 0.125f);
#pragma unroll
  for (int i = 0; i < 4; ++i)
#pragma unroll
    for (int j = 0; j < 4; ++j)
      SY[(ty4 + i) * NPAD + tx4 + j] = (ty4 + i == tx4 + j) ? 1.f : 0.f;
  __syncthreads();
  for (int mdeg = 12; mdeg >= 1; --mdeg) {   // Horner Taylor
    gemm64(SY, SZ, acc);                     // B*A'
    float inv = 1.f / (float)mdeg;
    float bn[4][4];
#pragma unroll
    for (int i = 0; i < 4; ++i)
#pragma unroll
      for (int j = 0; j < 4; ++j)
        bn[i][j] = acc[i][j] * inv + ((ty4 + i == tx4 + j) ? 1.f : 0.f);
    __syncthreads();
    store_tile(SY, bn);
    __syncthreads();
  }
  for (int q = 0; q < 3; ++q) {              // squarings (scale 1/8)
    gemm64(SY, SY, acc);
    __syncthreads();
    store_tile(SY, acc);
    __syncthreads();
  }
  // center = s*E*s
  load_mat(s, SZ);
  __syncthreads();
  gemm64(SY, SZ, acc);                       // E*s
  __syncthreads();
  store_tile(ST, acc);
  __syncthreads();
  gemm64(SZ, ST, acc);                       // s*(E*s)
  __syncthreads();
  store_tile(SY, acc);                       // SY = center
  __syncthreads();
  float c = ns_sqrt(SY, SZ, ST, red, 12);
  float rsc = 1.f / sqrtf(c);
#pragma unroll
  for (int i = 0; i < 4; ++i)
#pragma unroll
    for (int j = 0; j < 4; ++j)
      SZ[(ty4 + i) * NPAD + tx4 + j] *= rsc;  // csi
  load_mat(gsq, SY);
  __syncthreads();
  gemm64(SY, SZ, acc);                        // P = gsq*csi
#pragma unroll
  for (int i = 0; i < 4; ++i)
#pragma unroll
    for (int j = 0; j < 4; ++j)
      PT[(tx4 + j) * 64 + (ty4 + i)] = acc[i][j];
}

// out_b = P*x_b*P^T using PT only. 2048 blocks x 4 matrices.
__global__ __launch_bounds__(256) void k_out(const float* __restrict__ x,
                                             const float* __restrict__ PT,
                                             float* __restrict__ out) {
  __shared__ float SP[SLOT], SS[SLOT];
  const int tx4 = (threadIdx.x & 15) << 2;
  const int ty4 = (threadIdx.x >> 4) << 2;
  load_mat(PT, SP);
  __syncthreads();
  float acc[4][4];
  for (int mm = 0; mm < 4; ++mm) {
    size_t bidx = (size_t)blockIdx.x * 4 + mm;
    load_mat(x + bidx * 4096, SS);
    __syncthreads();
    gemm64(SP, SS, acc);                 // sum_k PT[k][r]*x[k][c] = P*x
    __syncthreads();
    store_tile_T(SS, acc);               // SS = (P*x)^T
    __syncthreads();
    gemm64(SS, SP, acc);                 // sum_k t1[r][k]*PT[k][c] = P*x*P^T
    float* ob = out + bidx * 4096;
#pragma unroll
    for (int i = 0; i < 4; ++i)
      *reinterpret_cast<float4*>(ob + (ty4 + i) * 64 + tx4) =
          make_float4(acc[i][0], acc[i][1], acc[i][2], acc[i][3]);
    __syncthreads();
  }
}

// ---------------- host ----------------

extern "C" void kernel_launch(void* const* d_in, const int* in_sizes, int n_in,
                              void* d_out, int out_size, void* d_ws, size_t ws_size,
                              hipStream_t stream) {
  (void)in_sizes; (void)n_in; (void)out_size; (void)ws_size;
  const float* x = (const float*)d_in[0];   // [8192,64,64]
  const float* G = (const float*)d_in[1];   // [64,64]
  float* out = (float*)d_out;
  float* wsf = (float*)d_ws;

  // scratch: partials live in d_out (overwritten by k_out at the end)
  float* part  = out;                       // 512*4096 floats
  float* mean0 = wsf;
  float* s_m   = wsf + 4096;
  float* si_m  = wsf + 8192;
  float* gsq   = wsf + 12288;
  float* meanT = wsf + 16384;
  float* PT    = wsf + 20480;

  // Chebyshev coefficients for log(lambda) on [a,b], degree 79, folded for
  // Paterson-Stockmeyer in Chebyshev basis (s=8, r=10).
  ChebArgs ca;
  {
    const double a = 0.035, b = 6.2;
    const double m = 0.5 * (a + b), h = 0.5 * (b - a);
    const double r = h / m;
    const double z = (1.0 - sqrt(1.0 - r * r)) / r;
    double c[80];
    c[0] = log(m) - log(1.0 + z * z);
    double zk = z;
    for (int k = 1; k < 80; ++k) {
      c[k] = 2.0 * ((k & 1) ? 1.0 : -1.0) * zk / (double)k;
      zk *= z;
    }
    double gg[10][8];
    for (int j = 0; j < 10; ++j) for (int i = 0; i < 8; ++i) gg[j][i] = 0.0;
    for (int j = 9; j >= 1; --j) {          // fold T_{js+i} = 2 T_i T_{js} - T_{js-i}
      for (int i = 1; i <= 7; ++i) {
        gg[j][i] = 2.0 * c[j * 8 + i];
        c[(j - 1) * 8 + (8 - i)] -= c[j * 8 + i];
      }
      gg[j][0] = c[j * 8];
    }
    for (int i = 0; i < 8; ++i) gg[0][i] = c[i];
    for (int j = 0; j < 10; ++j)
      for (int i = 0; i < 8; ++i) ca.g[j][i] = (float)gg[j][i];
    ca.mhat = (float)m;
    ca.invh = (float)(1.0 / h);
  }

  hipLaunchKernelGGL(k_mean_part, dim3(512), dim3(256), 0, stream, x, part);
  hipLaunchKernelGGL(k_reduce, dim3(16), dim3(256), 0, stream, part, 512,
                     1.f / 8192.f, mean0);
  hipLaunchKernelGGL(k_prep1, dim3(2), dim3(256), 0, stream, mean0, G, s_m, si_m, gsq);
  hipLaunchKernelGGL(k_logm_sum, dim3(512), dim3(256), 0, stream, x, si_m, part, ca);
  hipLaunchKernelGGL(k_reduce, dim3(16), dim3(256), 0, stream, part, 512,
                     1.f / 8192.f, meanT);
  hipLaunchKernelGGL(k_prep2, dim3(1), dim3(256), 0, stream, meanT, s_m, gsq, PT);
  hipLaunchKernelGGL(k_out, dim3(2048), dim3(256), 0, stream, x, PT, out);
}

// Round 2
// 844.965 us; speedup vs baseline: 2.3618x; 2.3618x over previous
//
#include <hip/hip_runtime.h>
#include <math.h>

// SPD normalization, eigh-free, MFMA-accelerated.
// All 64x64 GEMMs run on v_mfma_f32_16x16x32_f16 with f16 hi/lo split
// (3 products: hh, hl, lh -> ~2^-21 relative accuracy, fp32 accumulate).
// All chain matrices are symmetric (polynomials of one matrix), so the
// B-operand is fed by ROW reads (B symmetric => row-read == column-read).
// MFMA C fragments are stored "natural" (transposed), which for symmetric
// results is the matrix itself and keeps every LDS store k-contiguous.

typedef _Float16 half_t;
typedef __attribute__((ext_vector_type(8))) _Float16 f16x8;
typedef __attribute__((ext_vector_type(4))) float f32x4;

#define LOFF 4096            // lo-matrix offset inside a slot (half elements)
#define SLOTH 8192           // half elements per slot (hi 4096 + lo 4096)

struct ChebArgs {
  float g[9][8];             // folded Chebyshev-PS coefficients (r=9, s=8)
  float mhat, invh;          // U = (M - mhat*I) * invh
};

// ---------- LDS addressing (granule-XOR swizzle, granule = 8 f16 = 16B) ----------

__device__ __forceinline__ int swz(int row, int gran) {
  return row * 64 + ((gran ^ (row & 7)) << 3);
}

__device__ __forceinline__ f16x8 ld8(const half_t* p, int row, int gran) {
  union { uint4 u; f16x8 f; } c;
  c.u = *reinterpret_cast<const uint4*>(p + swz(row, gran));
  return c.f;
}

// ---------- fp32 <-> hi/lo f16 conversion helpers ----------

__device__ __forceinline__ void load16g(const float* __restrict__ g, float (&e)[16]) {
  int t = threadIdx.x;
  int row = t >> 2, k0 = (t & 3) << 4;
  const float4* g4 = reinterpret_cast<const float4*>(g + row * 64 + k0);
#pragma unroll
  for (int q = 0; q < 4; ++q) {
    float4 v = g4[q];
    e[4 * q + 0] = v.x; e[4 * q + 1] = v.y; e[4 * q + 2] = v.z; e[4 * q + 3] = v.w;
  }
}

__device__ __forceinline__ void e2slot(const float (&e)[16], half_t* __restrict__ D, float sc) {
  int t = threadIdx.x;
  int row = t >> 2, k0 = (t & 3) << 4;
#pragma unroll
  for (int gr = 0; gr < 2; ++gr) {
    union { half_t x[8]; uint4 u; } H, L;
#pragma unroll
    for (int j = 0; j < 8; ++j) {
      float v = e[8 * gr + j] * sc;
      half_t h = (half_t)v;
      H.x[j] = h;
      L.x[j] = (half_t)(v - (float)h);
    }
    int ph = swz(row, (k0 >> 3) + gr);
    *reinterpret_cast<uint4*>(D + ph) = H.u;
    *reinterpret_cast<uint4*>(D + LOFF + ph) = L.u;
  }
}

__device__ __forceinline__ void g2slot(const float* __restrict__ g, half_t* __restrict__ D,
                                       float sc) {
  float e[16];
  load16g(g, e);
  e2slot(e, D, sc);
}

__device__ __forceinline__ void id2slot(half_t* __restrict__ D) {
  int t = threadIdx.x;
  int row = t >> 2, k0 = (t & 3) << 4;
#pragma unroll
  for (int gr = 0; gr < 2; ++gr) {
    union { half_t x[8]; uint4 u; } H, L;
#pragma unroll
    for (int j = 0; j < 8; ++j) {
      int col = k0 + 8 * gr + j;
      H.x[j] = (col == row) ? (half_t)1.f : (half_t)0.f;
      L.x[j] = (half_t)0.f;
    }
    int ph = swz(row, (k0 >> 3) + gr);
    *reinterpret_cast<uint4*>(D + ph) = H.u;
    *reinterpret_cast<uint4*>(D + LOFF + ph) = L.u;
  }
}

__device__ __forceinline__ void slot2g(const half_t* __restrict__ D, float* __restrict__ dst,
                                       float sc) {
  int t = threadIdx.x;
  int row = t >> 2, k0 = (t & 3) << 4;
#pragma unroll
  for (int gr = 0; gr < 2; ++gr) {
    int ph = swz(row, (k0 >> 3) + gr);
    union { uint4 u; f16x8 f; } H, L;
    H.u = *reinterpret_cast<const uint4*>(D + ph);
    L.u = *reinterpret_cast<const uint4*>(D + LOFF + ph);
    float o[8];
#pragma unroll
    for (int j = 0; j < 8; ++j) o[j] = ((float)H.f[j] + (float)L.f[j]) * sc;
    *reinterpret_cast<float4*>(dst + row * 64 + k0 + 8 * gr) =
        make_float4(o[0], o[1], o[2], o[3]);
    *reinterpret_cast<float4*>(dst + row * 64 + k0 + 8 * gr + 4) =
        make_float4(o[4], o[5], o[6], o[7]);
  }
}

// ---------- per-wave fragment geometry ----------
// 4 waves: wave (qr,qc) owns C rows 32qr..+31, cols 32qc..+31 (2x2 16x16 frags).
// C frag (mf,nf): element [32qr+16mf+4g+r][32qc+16nf+cl], cl=lane&15, g=lane>>4.

__device__ __forceinline__ bool dgf(int mf, int nf, int r) {
  int t = threadIdx.x, wid = t >> 6, lane = t & 63;
  return (32 * (wid >> 1) + 16 * mf + 4 * (lane >> 4) + r) ==
         (32 * (wid & 1) + 16 * nf + (lane & 15));
}

// C = Z_A * Z_B^T, both operands ROW-read from hi/lo slots. fp32 accumulate.
__device__ __forceinline__ void gemm_hl(const half_t* __restrict__ A,
                                        const half_t* __restrict__ B, f32x4 (&acc)[2][2]) {
  int t = threadIdx.x, wid = t >> 6, lane = t & 63;
  int cl = lane & 15, g = lane >> 4;
  int qr = wid >> 1, qc = wid & 1;
#pragma unroll
  for (int mf = 0; mf < 2; ++mf)
#pragma unroll
    for (int nf = 0; nf < 2; ++nf) acc[mf][nf] = (f32x4){0.f, 0.f, 0.f, 0.f};
#pragma unroll
  for (int kh = 0; kh < 2; ++kh) {
    int gran = g + 4 * kh;
    f16x8 ah[2], al[2], bh[2], bl[2];
#pragma unroll
    for (int mf = 0; mf < 2; ++mf) {
      int r = 32 * qr + 16 * mf + cl;
      ah[mf] = ld8(A, r, gran);
      al[mf] = ld8(A + LOFF, r, gran);
    }
#pragma unroll
    for (int nf = 0; nf < 2; ++nf) {
      int r = 32 * qc + 16 * nf + cl;
      bh[nf] = ld8(B, r, gran);
      bl[nf] = ld8(B + LOFF, r, gran);
    }
#pragma unroll
    for (int mf = 0; mf < 2; ++mf)
#pragma unroll
      for (int nf = 0; nf < 2; ++nf) {
        acc[mf][nf] = __builtin_amdgcn_mfma_f32_16x16x32_f16(ah[mf], bh[nf], acc[mf][nf], 0, 0, 0);
        acc[mf][nf] = __builtin_amdgcn_mfma_f32_16x16x32_f16(ah[mf], bl[nf], acc[mf][nf], 0, 0, 0);
        acc[mf][nf] = __builtin_amdgcn_mfma_f32_16x16x32_f16(al[mf], bh[nf], acc[mf][nf], 0, 0, 0);
      }
  }
}

// Store C fragments "natural" (i.e. stores C^T; == C for symmetric C) to hi/lo slot.
__device__ __forceinline__ void st_nat(half_t* __restrict__ D, const f32x4 (&a)[2][2], float sc) {
  int t = threadIdx.x, wid = t >> 6, lane = t & 63;
  int cl = lane & 15, g = lane >> 4;
  int qr = wid >> 1, qc = wid & 1;
#pragma unroll
  for (int mf = 0; mf < 2; ++mf)
#pragma unroll
    for (int nf = 0; nf < 2; ++nf) {
      int row = 32 * qc + 16 * nf + cl;
      int colb = 32 * qr + 16 * mf + 4 * g;
      int gran = colb >> 3, pos = colb & 7;
      int ph = row * 64 + ((gran ^ (row & 7)) << 3) + pos;
      union { half_t x[4]; uint2 u; } H, L;
#pragma unroll
      for (int r = 0; r < 4; ++r) {
        float v = a[mf][nf][r] * sc;
        half_t h = (half_t)v;
        H.x[r] = h;
        L.x[r] = (half_t)(v - (float)h);
      }
      *reinterpret_cast<uint2*>(D + ph) = H.u;
      *reinterpret_cast<uint2*>(D + LOFF + ph) = L.u;
    }
}

// Store C fragments natural to global fp32 (C^T; == C for symmetric C).
__device__ __forceinline__ void st_f32g(float* __restrict__ dst, const f32x4 (&a)[2][2],
                                        float sc) {
  int t = threadIdx.x, wid = t >> 6, lane = t & 63;
  int cl = lane & 15, g = lane >> 4;
  int qr = wid >> 1, qc = wid & 1;
#pragma unroll
  for (int mf = 0; mf < 2; ++mf)
#pragma unroll
    for (int nf = 0; nf < 2; ++nf) {
      int row = 32 * qc + 16 * nf + cl;
      int colb = 32 * qr + 16 * mf + 4 * g;
      *reinterpret_cast<float4*>(dst + row * 64 + colb) =
          make_float4(a[mf][nf][0] * sc, a[mf][nf][1] * sc, a[mf][nf][2] * sc,
                      a[mf][nf][3] * sc);
    }
}

__device__ __forceinline__ float block_reduce_sum(float v, float* red) {
  int t = threadIdx.x;
  red[t] = v;
  __syncthreads();
#pragma unroll
  for (int sft = 128; sft >= 1; sft >>= 1) {
    if (t < sft) red[t] += red[t + sft];
    __syncthreads();
  }
  float r = red[0];
  __syncthreads();
  return r;
}

// Coupled Newton-Schulz on slots: Y=(A/c)^{1/2}, Z=(A/c)^{-1/2}. Caller pre-loads
// Y = A/c, Z = I. All iterates symmetric.
__device__ void ns_mfma(half_t* Y, half_t* Z, half_t* T, int iters) {
  for (int it = 0; it < iters; ++it) {
    f32x4 a1[2][2];
    gemm_hl(Z, Y, a1);                       // Z*Y
    f32x4 tf[2][2];
#pragma unroll
    for (int mf = 0; mf < 2; ++mf)
#pragma unroll
      for (int nf = 0; nf < 2; ++nf)
#pragma unroll
        for (int r = 0; r < 4; ++r)
          tf[mf][nf][r] = (dgf(mf, nf, r) ? 1.5f : 0.f) - 0.5f * a1[mf][nf][r];
    st_nat(T, tf, 1.f);                      // T not an operand of the gemm above
    __syncthreads();
    f32x4 aY[2][2], aZ[2][2];
    gemm_hl(Y, T, aY);                       // Y*T
    gemm_hl(T, Z, aZ);                       // T*Z
    __syncthreads();                         // all waves done reading Y,Z,T
    st_nat(Y, aY, 1.f);
    st_nat(Z, aZ, 1.f);
    __syncthreads();
  }
}

// ---------------- kernels ----------------

// Partial batch mean: 512 blocks x 256 thr, 16 batches each -> part[blk][4096]
__global__ void k_mean_part(const float* __restrict__ x, float* __restrict__ part) {
  float4 s[4];
#pragma unroll
  for (int q = 0; q < 4; ++q) s[q] = make_float4(0.f, 0.f, 0.f, 0.f);
  int base = blockIdx.x * 16;
  for (int b = 0; b < 16; ++b) {
    const float4* x4 = reinterpret_cast<const float4*>(x + (size_t)(base + b) * 4096);
#pragma unroll
    for (int q = 0; q < 4; ++q) {
      float4 v = x4[threadIdx.x + (q << 8)];
      s[q].x += v.x; s[q].y += v.y; s[q].z += v.z; s[q].w += v.w;
    }
  }
  float4* p4 = reinterpret_cast<float4*>(part + (size_t)blockIdx.x * 4096);
#pragma unroll
  for (int q = 0; q < 4; ++q) p4[threadIdx.x + (q << 8)] = s[q];
}

__global__ void k_reduce(const float* __restrict__ part, int np, float scale,
                         float* __restrict__ o) {
  int j = blockIdx.x * 256 + threadIdx.x;
  float s = 0.f;
  for (int p = 0; p < np; ++p) s += part[(size_t)p * 4096 + j];
  o[j] = s * scale;
}

// Block 0: s=sqrtm(mean0), si=invsqrtm(mean0). Block 1: gsq=sqrtm(G).
__global__ __launch_bounds__(256) void k_prep1(const float* __restrict__ mean0,
                                               const float* __restrict__ G,
                                               float* __restrict__ s_out,
                                               float* __restrict__ si_out,
                                               float* __restrict__ gsq_out) {
  __shared__ __align__(16) half_t lds[3 * SLOTH];
  __shared__ float red[256];
  half_t *Y = lds, *Z = lds + SLOTH, *T = lds + 2 * SLOTH;
  const float* src = blockIdx.x ? G : mean0;
  int t = threadIdx.x, row = t >> 2, k0 = (t & 3) << 4;
  float e[16];
  load16g(src, e);
  float tl = ((t & 3) == (row >> 4)) ? e[row & 15] : 0.f;
  float m = block_reduce_sum(tl, red) * (1.f / 64.f);
  float fl = 0.f;
#pragma unroll
  for (int j = 0; j < 16; ++j) {
    float d = e[j] - ((k0 + j == row) ? m : 0.f);
    fl = fmaf(d, d, fl);
  }
  float c = m + sqrtf(block_reduce_sum(fl, red));   // >= lambda_max
  e2slot(e, Y, 1.f / c);
  id2slot(Z);
  __syncthreads();
  ns_mfma(Y, Z, T, blockIdx.x ? 9 : 6);
  float sc = sqrtf(c);
  if (blockIdx.x == 0) {
    slot2g(Y, s_out, sc);
    slot2g(Z, si_out, 1.f / sc);
  } else {
    slot2g(Y, gsq_out, sc);
  }
}

// Heavy kernel: per matrix M = si*x*si; U=(M-m)/h; logm via Chebyshev-PS
// (s=8, r=9, degree 71); accumulate sum of logs -> part[blk][4096].
__global__ __launch_bounds__(256, 2) void k_logm_sum(const float* __restrict__ x,
                                                     const float* __restrict__ si,
                                                     float* __restrict__ part,
                                                     ChebArgs ca) {
  __shared__ __align__(16) half_t lds[4 * SLOTH];   // 64 KB
  half_t *SI = lds, *P0 = lds + SLOTH, *P1 = lds + 2 * SLOTH, *P2 = lds + 3 * SLOTH;

  g2slot(si, SI, 1.f);

  f32x4 sum[2][2];
#pragma unroll
  for (int mf = 0; mf < 2; ++mf)
#pragma unroll
    for (int nf = 0; nf < 2; ++nf) sum[mf][nf] = (f32x4){0.f, 0.f, 0.f, 0.f};

  f32x4 tt[7][2][2], acc[2][2], bcur[2][2], bprev[2][2];

#pragma unroll 1
  for (int mm = 0; mm < 16; ++mm) {
    const float* xb = x + ((size_t)blockIdx.x * 16 + mm) * 4096;
    g2slot(xb, P0, 1.f);
    __syncthreads();

    gemm_hl(P0, SI, acc);                     // x * si
    st_nat(P1, acc, 1.f);                     // P1 = (x si)^T = si x
    __syncthreads();

    gemm_hl(P1, SI, acc);                     // (si x) * si = M (symmetric)
#pragma unroll
    for (int mf = 0; mf < 2; ++mf)
#pragma unroll
      for (int nf = 0; nf < 2; ++nf)
#pragma unroll
        for (int r = 0; r < 4; ++r)
          tt[0][mf][nf][r] =
              (acc[mf][nf][r] - (dgf(mf, nf, r) ? ca.mhat : 0.f)) * ca.invh;  // T1 = U
    st_nat(P0, tt[0], 1.f);                   // P0 = U (x dead)
    __syncthreads();

    gemm_hl(P0, P0, acc);                     // U*U
#pragma unroll
    for (int mf = 0; mf < 2; ++mf)
#pragma unroll
      for (int nf = 0; nf < 2; ++nf)
#pragma unroll
        for (int r = 0; r < 4; ++r)
          tt[1][mf][nf][r] = 2.f * acc[mf][nf][r] - (dgf(mf, nf, r) ? 1.f : 0.f);
    st_nat(P1, tt[1], 1.f);                   // T2 -> P1
    __syncthreads();

    // T3..T7, ping-pong P1/P2, U fixed at P0
#pragma unroll
    for (int n = 3; n <= 7; ++n) {
      half_t* rd = ((n - 3) & 1) ? P2 : P1;
      half_t* wr = ((n - 3) & 1) ? P1 : P2;
      gemm_hl(P0, rd, acc);                   // U * T_{n-1}
#pragma unroll
      for (int mf = 0; mf < 2; ++mf)
#pragma unroll
        for (int nf = 0; nf < 2; ++nf)
#pragma unroll
          for (int r = 0; r < 4; ++r)
            tt[n - 1][mf][nf][r] = 2.f * acc[mf][nf][r] - tt[n - 3][mf][nf][r];
      st_nat(wr, tt[n - 1], 1.f);
      __syncthreads();
    }

    // V = T8 = 2*U*T7 - T6 ; T7 lives in P2
    gemm_hl(P0, P2, acc);
    {
      f32x4 vv[2][2];
#pragma unroll
      for (int mf = 0; mf < 2; ++mf)
#pragma unroll
        for (int nf = 0; nf < 2; ++nf)
#pragma unroll
          for (int r = 0; r < 4; ++r)
            vv[mf][nf][r] = 2.f * acc[mf][nf][r] - tt[5][mf][nf][r];
      st_nat(P1, vv, 1.f);                    // V -> P1 (T6 dead)
    }
    __syncthreads();                          // clears readers of P0, P2

    // Clenshaw over 9 blocks: bcur=Q8, bprev=0; b ping-pong P0/P2, V at P1
#pragma unroll
    for (int mf = 0; mf < 2; ++mf)
#pragma unroll
      for (int nf = 0; nf < 2; ++nf)
#pragma unroll
        for (int r = 0; r < 4; ++r) {
          float q = dgf(mf, nf, r) ? ca.g[8][0] : 0.f;
#pragma unroll
          for (int tx = 1; tx <= 7; ++tx) q = fmaf(ca.g[8][tx], tt[tx - 1][mf][nf][r], q);
          bcur[mf][nf][r] = q;
          bprev[mf][nf][r] = 0.f;
        }

#pragma unroll 1
    for (int jj = 7; jj >= 1; --jj) {
      half_t* bs = ((7 - jj) & 1) ? P2 : P0;
      st_nat(bs, bcur, 1.f);
      __syncthreads();
      gemm_hl(P1, bs, acc);                   // V * b_{jj+1}
#pragma unroll
      for (int mf = 0; mf < 2; ++mf)
#pragma unroll
        for (int nf = 0; nf < 2; ++nf)
#pragma unroll
          for (int r = 0; r < 4; ++r) {
            float q = dgf(mf, nf, r) ? ca.g[jj][0] : 0.f;
#pragma unroll
            for (int tx = 1; tx <= 7; ++tx) q = fmaf(ca.g[jj][tx], tt[tx - 1][mf][nf][r], q);
            float bn = q + 2.f * acc[mf][nf][r] - bprev[mf][nf][r];
            bprev[mf][nf][r] = bcur[mf][nf][r];
            bcur[mf][nf][r] = bn;
          }
    }

    st_nat(P2, bcur, 1.f);                    // b_1 (P2 last read 2 gemms ago)
    __syncthreads();
    gemm_hl(P1, P2, acc);                     // V * b_1
#pragma unroll
    for (int mf = 0; mf < 2; ++mf)
#pragma unroll
      for (int nf = 0; nf < 2; ++nf)
#pragma unroll
        for (int r = 0; r < 4; ++r) {
          float q = dgf(mf, nf, r) ? ca.g[0][0] : 0.f;
#pragma unroll
          for (int tx = 1; tx <= 7; ++tx) q = fmaf(ca.g[0][tx], tt[tx - 1][mf][nf][r], q);
          sum[mf][nf][r] += q + acc[mf][nf][r] - bprev[mf][nf][r];
        }
    // next iteration overwrites P0 (final gemm reads P1,P2 only -> safe)
  }
  st_f32g(part + (size_t)blockIdx.x * 4096, sum, 1.f);
}

// E=expm(meanT) (Taylor deg 12, ||meanT|| small); center=s*E*s; csi=invsqrtm(center);
// P = gsq*csi stored row-major to global. One block.
__global__ __launch_bounds__(256) void k_prep2(const float* __restrict__ meanT,
                                               const float* __restrict__ s,
                                               const float* __restrict__ gsq,
                                               float* __restrict__ P_out) {
  __shared__ __align__(16) half_t lds[5 * SLOTH];
  __shared__ float red[256];
  half_t *S0 = lds, *S1 = lds + SLOTH, *S2 = lds + 2 * SLOTH, *S3 = lds + 3 * SLOTH,
         *S4 = lds + 4 * SLOTH;
  g2slot(meanT, S0, 1.f);                     // A'
  id2slot(S1);                                // E iterate
  g2slot(s, S3, 1.f);
  g2slot(gsq, S4, 1.f);
  __syncthreads();

  half_t* cur = S1;
  half_t* oth = S2;
  f32x4 a[2][2];
#pragma unroll 1
  for (int k = 12; k >= 1; --k) {             // Horner: B <- I + A*B/k
    gemm_hl(cur, S0, a);
    float inv = 1.f / (float)k;
    f32x4 en[2][2];
#pragma unroll
    for (int mf = 0; mf < 2; ++mf)
#pragma unroll
      for (int nf = 0; nf < 2; ++nf)
#pragma unroll
        for (int r = 0; r < 4; ++r)
          en[mf][nf][r] = a[mf][nf][r] * inv + (dgf(mf, nf, r) ? 1.f : 0.f);
    st_nat(oth, en, 1.f);
    __syncthreads();
    half_t* tmp = cur; cur = oth; oth = tmp;
  }
  // cur == S1 holds E. center = s*E*s:
  gemm_hl(cur, S3, a);                        // E*s
  st_nat(S0, a, 1.f);                         // S0 = s*E (A' dead)
  __syncthreads();
  gemm_hl(S0, S3, a);                         // (s*E)*s = center (symmetric)
  float tl = 0.f;
#pragma unroll
  for (int mf = 0; mf < 2; ++mf)
#pragma unroll
    for (int nf = 0; nf < 2; ++nf)
#pragma unroll
      for (int r = 0; r < 4; ++r)
        if (dgf(mf, nf, r)) tl += a[mf][nf][r];
  float m = block_reduce_sum(tl, red) * (1.f / 64.f);
  float fl = 0.f;
#pragma unroll
  for (int mf = 0; mf < 2; ++mf)
#pragma unroll
    for (int nf = 0; nf < 2; ++nf)
#pragma unroll
      for (int r = 0; r < 4; ++r) {
        float d = a[mf][nf][r] - (dgf(mf, nf, r) ? m : 0.f);
        fl = fmaf(d, d, fl);
      }
  float c = m + sqrtf(block_reduce_sum(fl, red));
  st_nat(S1, a, 1.f / c);                     // Y = center/c
  id2slot(S2);                                // Z = I
  __syncthreads();
  ns_mfma(S1, S2, S3, 9);                     // Z = (center/c)^{-1/2}
  gemm_hl(S2, S4, a);                         // Z*gsq
  st_f32g(P_out, a, 1.f / sqrtf(c));          // stores (Z*gsq)^T/sqrt(c) = gsq*csi = P
}

// out_b = P*x_b*P^T. 2048 blocks x 4 matrices.
__global__ __launch_bounds__(256) void k_out(const float* __restrict__ x,
                                             const float* __restrict__ P,
                                             float* __restrict__ out) {
  __shared__ __align__(16) half_t lds[3 * SLOTH];
  half_t *SP = lds, *SX = lds + SLOTH, *ST = lds + 2 * SLOTH;
  g2slot(P, SP, 1.f);
  __syncthreads();
  f32x4 a[2][2];
#pragma unroll 1
  for (int mm = 0; mm < 4; ++mm) {
    size_t b = (size_t)blockIdx.x * 4 + mm;
    g2slot(x + b * 4096, SX, 1.f);
    __syncthreads();
    gemm_hl(SX, SP, a);                       // x * P^T
    st_nat(ST, a, 1.f);                       // ST = P*x
    __syncthreads();
    gemm_hl(ST, SP, a);                       // (P*x) * P^T  (symmetric)
    st_f32g(out + b * 4096, a, 1.f);
    // next g2slot(SX) is safe: remaining readers touch ST/SP only
  }
}

// ---------------- host ----------------

extern "C" void kernel_launch(void* const* d_in, const int* in_sizes, int n_in,
                              void* d_out, int out_size, void* d_ws, size_t ws_size,
                              hipStream_t stream) {
  (void)in_sizes; (void)n_in; (void)out_size; (void)ws_size;
  const float* x = (const float*)d_in[0];   // [8192,64,64]
  const float* G = (const float*)d_in[1];   // [64,64]
  float* out = (float*)d_out;
  float* wsf = (float*)d_ws;

  float* part  = out;                       // 512*4096 floats (overwritten by k_out)
  float* mean0 = wsf;
  float* s_m   = wsf + 4096;
  float* si_m  = wsf + 8192;
  float* gsq   = wsf + 12288;
  float* meanT = wsf + 16384;
  float* Pm    = wsf + 20480;

  // Chebyshev coefficients for log on [a,b], degree 71, PS-folded (s=8, r=9).
  ChebArgs ca;
  {
    const double a = 0.04, b = 6.0;
    const double m = 0.5 * (a + b), h = 0.5 * (b - a);
    const double r = h / m;
    const double z = (1.0 - sqrt(1.0 - r * r)) / r;
    double c[72];
    c[0] = log(m) - log(1.0 + z * z);
    double zk = z;
    for (int k = 1; k < 72; ++k) {
      c[k] = 2.0 * ((k & 1) ? 1.0 : -1.0) * zk / (double)k;
      zk *= z;
    }
    double gg[9][8];
    for (int j = 0; j < 9; ++j) for (int i = 0; i < 8; ++i) gg[j][i] = 0.0;
    for (int j = 8; j >= 1; --j) {
      for (int i = 1; i <= 7; ++i) {
        gg[j][i] = 2.0 * c[j * 8 + i];
        c[(j - 1) * 8 + (8 - i)] -= c[j * 8 + i];
      }
      gg[j][0] = c[j * 8];
    }
    for (int i = 0; i < 8; ++i) gg[0][i] = c[i];
    for (int j = 0; j < 9; ++j)
      for (int i = 0; i < 8; ++i) ca.g[j][i] = (float)gg[j][i];
    ca.mhat = (float)m;
    ca.invh = (float)(1.0 / h);
  }

  hipLaunchKernelGGL(k_mean_part, dim3(512), dim3(256), 0, stream, x, part);
  hipLaunchKernelGGL(k_reduce, dim3(16), dim3(256), 0, stream, part, 512,
                     1.f / 8192.f, mean0);
  hipLaunchKernelGGL(k_prep1, dim3(2), dim3(256), 0, stream, mean0, G, s_m, si_m, gsq);
  hipLaunchKernelGGL(k_logm_sum, dim3(512), dim3(256), 0, stream, x, si_m, part, ca);
  hipLaunchKernelGGL(k_reduce, dim3(16), dim3(256), 0, stream, part, 512,
                     1.f / 8192.f, meanT);
  hipLaunchKernelGGL(k_prep2, dim3(1), dim3(256), 0, stream, meanT, s_m, gsq, Pm);
  hipLaunchKernelGGL(k_out, dim3(2048), dim3(256), 0, stream, x, Pm, out);
}

// Round 4
// 587.559 us; speedup vs baseline: 3.3965x; 1.4381x over previous
//
#include <hip/hip_runtime.h>
#include <math.h>

// SPD normalization, eigh-free, MFMA (f16 hi/lo split, fp32 accumulate).
// GEMM convention: gemm(A,B) computes C = A * B^T with both operands read as
// ROW slices; st_nat stores C^T. For symmetric B this gives A*B for any A.

typedef _Float16 half_t;
typedef __attribute__((ext_vector_type(8))) _Float16 f16x8;
typedef __attribute__((ext_vector_type(2))) _Float16 f16x2;
typedef __attribute__((ext_vector_type(2))) __fp16 fp16x2_raw;
typedef __attribute__((ext_vector_type(4))) float f32x4;

__device__ __forceinline__ f16x2 cvt_pk(float a, float b) {
  union { fp16x2_raw r; f16x2 f; } u;
  u.r = __builtin_amdgcn_cvt_pkrtz(a, b);
  return u.f;
}

#define LOFF 4096            // lo-matrix offset inside a slot (half elements)
#define SLOTH 8192           // half elements per slot (hi 4096 + lo 4096)

struct ChebL { float g[8][8]; float mhat, invh; };   // log,  s=8, r=8 (deg 63)
struct ChebS { float g[8][4]; float mhat, invh; };   // sqrt, s=4, r=8 (deg 31)

struct Frag8 { f16x8 h[2][2]; f16x8 l[2][2]; };      // [frag][kh]

// ---------- LDS addressing (granule-XOR swizzle, granule = 8 f16 = 16B) ----------

__device__ __forceinline__ int swz(int row, int gran) {
  return row * 64 + ((gran ^ (row & 7)) << 3);
}

__device__ __forceinline__ f16x8 ld8(const half_t* p, int row, int gran) {
  union { uint4 u; f16x8 f; } c;
  c.u = *reinterpret_cast<const uint4*>(p + swz(row, gran));
  return c.f;
}

// ---------- conversions ----------

__device__ __forceinline__ void load16g(const float* __restrict__ g, float (&e)[16]) {
  int t = threadIdx.x;
  int row = t >> 2, k0 = (t & 3) << 4;
  const float4* g4 = reinterpret_cast<const float4*>(g + row * 64 + k0);
#pragma unroll
  for (int q = 0; q < 4; ++q) {
    float4 v = g4[q];
    e[4 * q + 0] = v.x; e[4 * q + 1] = v.y; e[4 * q + 2] = v.z; e[4 * q + 3] = v.w;
  }
}

// v = e*sc - (col==row)*dsub, split hi/lo, store to slot
__device__ __forceinline__ void e2slot_d(const float (&e)[16], half_t* __restrict__ D,
                                         float sc, float dsub) {
  int t = threadIdx.x, row = t >> 2, k0 = (t & 3) << 4;
#pragma unroll
  for (int gr = 0; gr < 2; ++gr) {
    union { f16x8 f; uint4 u; } H, L;
#pragma unroll
    for (int jp = 0; jp < 8; jp += 2) {
      int c0 = k0 + 8 * gr + jp;
      float v0 = e[8 * gr + jp] * sc - ((c0 == row) ? dsub : 0.f);
      float v1 = e[8 * gr + jp + 1] * sc - ((c0 + 1 == row) ? dsub : 0.f);
      f16x2 hp = cvt_pk(v0, v1);
      f16x2 lp = cvt_pk(v0 - (float)hp[0], v1 - (float)hp[1]);
      H.f[jp] = hp[0]; H.f[jp + 1] = hp[1];
      L.f[jp] = lp[0]; L.f[jp + 1] = lp[1];
    }
    int ph = swz(row, (k0 >> 3) + gr);
    *reinterpret_cast<uint4*>(D + ph) = H.u;
    *reinterpret_cast<uint4*>(D + LOFF + ph) = L.u;
  }
}

__device__ __forceinline__ void g2slot(const float* __restrict__ g, half_t* __restrict__ D) {
  float e[16];
  load16g(g, e);
  e2slot_d(e, D, 1.f, 0.f);
}

__device__ __forceinline__ void slot2e(const half_t* __restrict__ D, float (&e)[16]) {
  int t = threadIdx.x, row = t >> 2, k0 = (t & 3) << 4;
#pragma unroll
  for (int gr = 0; gr < 2; ++gr) {
    int ph = swz(row, (k0 >> 3) + gr);
    union { uint4 u; f16x8 f; } H, L;
    H.u = *reinterpret_cast<const uint4*>(D + ph);
    L.u = *reinterpret_cast<const uint4*>(D + LOFF + ph);
#pragma unroll
    for (int j = 0; j < 8; ++j) e[8 * gr + j] = (float)H.f[j] + (float)L.f[j];
  }
}

// ---------- fragment loads ----------

__device__ __forceinline__ Frag8 ld_rowfrags(const half_t* __restrict__ S, int q) {
  int t = threadIdx.x, lane = t & 63, cl = lane & 15, g = lane >> 4;
  Frag8 F;
#pragma unroll
  for (int f = 0; f < 2; ++f)
#pragma unroll
    for (int kh = 0; kh < 2; ++kh) {
      int row = 32 * q + 16 * f + cl;
      F.h[f][kh] = ld8(S, row, g + 4 * kh);
      F.l[f][kh] = ld8(S + LOFF, row, g + 4 * kh);
    }
  return F;
}

__device__ __forceinline__ Frag8 ld_rowfrags_g(const float* __restrict__ M, int q) {
  int t = threadIdx.x, lane = t & 63, cl = lane & 15, g = lane >> 4;
  Frag8 F;
#pragma unroll
  for (int f = 0; f < 2; ++f)
#pragma unroll
    for (int kh = 0; kh < 2; ++kh) {
      int row = 32 * q + 16 * f + cl;
      const float* p = M + row * 64 + 8 * (g + 4 * kh);
      float4 a = *reinterpret_cast<const float4*>(p);
      float4 b = *reinterpret_cast<const float4*>(p + 4);
      float v[8] = {a.x, a.y, a.z, a.w, b.x, b.y, b.z, b.w};
      f16x8 H, L;
#pragma unroll
      for (int jp = 0; jp < 8; jp += 2) {
        f16x2 hp = cvt_pk(v[jp], v[jp + 1]);
        f16x2 lp = cvt_pk(v[jp] - (float)hp[0], v[jp + 1] - (float)hp[1]);
        H[jp] = hp[0]; H[jp + 1] = hp[1];
        L[jp] = lp[0]; L[jp + 1] = lp[1];
      }
      F.h[f][kh] = H; F.l[f][kh] = L;
    }
  return F;
}

// C-frag-layout scalar read (prep only)
__device__ __forceinline__ void ld_cfrags(const half_t* __restrict__ S, f32x4 (&o)[2][2]) {
  int t = threadIdx.x, lane = t & 63, cl = lane & 15, g = lane >> 4;
  int wid = t >> 6, qr = wid >> 1, qc = wid & 1;
#pragma unroll
  for (int mf = 0; mf < 2; ++mf)
#pragma unroll
    for (int nf = 0; nf < 2; ++nf)
#pragma unroll
      for (int r = 0; r < 4; ++r) {
        int row = 32 * qr + 16 * mf + 4 * g + r;
        int col = 32 * qc + 16 * nf + cl;
        int ph = row * 64 + (((col >> 3) ^ (row & 7)) << 3) + (col & 7);
        o[mf][nf][r] = (float)S[ph] + (float)S[LOFF + ph];
      }
}

// ---------- gemm cores ----------

__device__ __forceinline__ void mfma3(const f16x8& ah, const f16x8& al,
                                      const f16x8& bh, const f16x8& bl, f32x4& acc) {
  acc = __builtin_amdgcn_mfma_f32_16x16x32_f16(ah, bh, acc, 0, 0, 0);
  acc = __builtin_amdgcn_mfma_f32_16x16x32_f16(ah, bl, acc, 0, 0, 0);
  acc = __builtin_amdgcn_mfma_f32_16x16x32_f16(al, bh, acc, 0, 0, 0);
}

#define ZACC(acc) { _Pragma("unroll") for (int _m=0;_m<2;++_m) _Pragma("unroll") \
  for (int _n=0;_n<2;++_n) acc[_m][_n] = (f32x4){0.f,0.f,0.f,0.f}; }

__device__ __forceinline__ void gemm_sA_rB(const half_t* __restrict__ A, const Frag8& B,
                                           f32x4 (&acc)[2][2]) {
  int t = threadIdx.x, lane = t & 63, cl = lane & 15, g = lane >> 4;
  int qr = (t >> 6) >> 1;
  ZACC(acc);
#pragma unroll
  for (int kh = 0; kh < 2; ++kh) {
    f16x8 ah[2], al[2];
#pragma unroll
    for (int mf = 0; mf < 2; ++mf) {
      int row = 32 * qr + 16 * mf + cl;
      ah[mf] = ld8(A, row, g + 4 * kh);
      al[mf] = ld8(A + LOFF, row, g + 4 * kh);
    }
#pragma unroll
    for (int mf = 0; mf < 2; ++mf)
#pragma unroll
      for (int nf = 0; nf < 2; ++nf)
        mfma3(ah[mf], al[mf], B.h[nf][kh], B.l[nf][kh], acc[mf][nf]);
  }
}

__device__ __forceinline__ void gemm_rA_sB(const Frag8& A, const half_t* __restrict__ B,
                                           f32x4 (&acc)[2][2]) {
  int t = threadIdx.x, lane = t & 63, cl = lane & 15, g = lane >> 4;
  int qc = (t >> 6) & 1;
  ZACC(acc);
#pragma unroll
  for (int kh = 0; kh < 2; ++kh) {
    f16x8 bh[2], bl[2];
#pragma unroll
    for (int nf = 0; nf < 2; ++nf) {
      int row = 32 * qc + 16 * nf + cl;
      bh[nf] = ld8(B, row, g + 4 * kh);
      bl[nf] = ld8(B + LOFF, row, g + 4 * kh);
    }
#pragma unroll
    for (int mf = 0; mf < 2; ++mf)
#pragma unroll
      for (int nf = 0; nf < 2; ++nf)
        mfma3(A.h[mf][kh], A.l[mf][kh], bh[nf], bl[nf], acc[mf][nf]);
  }
}

__device__ __forceinline__ void gemm_sA_sB(const half_t* __restrict__ A,
                                           const half_t* __restrict__ B,
                                           f32x4 (&acc)[2][2]) {
  int t = threadIdx.x, lane = t & 63, cl = lane & 15, g = lane >> 4;
  int wid = t >> 6, qr = wid >> 1, qc = wid & 1;
  ZACC(acc);
#pragma unroll
  for (int kh = 0; kh < 2; ++kh) {
    f16x8 ah[2], al[2], bh[2], bl[2];
#pragma unroll
    for (int mf = 0; mf < 2; ++mf) {
      int row = 32 * qr + 16 * mf + cl;
      ah[mf] = ld8(A, row, g + 4 * kh);
      al[mf] = ld8(A + LOFF, row, g + 4 * kh);
    }
#pragma unroll
    for (int nf = 0; nf < 2; ++nf) {
      int row = 32 * qc + 16 * nf + cl;
      bh[nf] = ld8(B, row, g + 4 * kh);
      bl[nf] = ld8(B + LOFF, row, g + 4 * kh);
    }
#pragma unroll
    for (int mf = 0; mf < 2; ++mf)
#pragma unroll
      for (int nf = 0; nf < 2; ++nf)
        mfma3(ah[mf], al[mf], bh[nf], bl[nf], acc[mf][nf]);
  }
}

// store C^T (== C for symmetric) to hi/lo slot
__device__ __forceinline__ void st_nat(half_t* __restrict__ D, const f32x4 (&a)[2][2]) {
  int t = threadIdx.x, lane = t & 63, cl = lane & 15, g = lane >> 4;
  int wid = t >> 6, qr = wid >> 1, qc = wid & 1;
#pragma unroll
  for (int mf = 0; mf < 2; ++mf)
#pragma unroll
    for (int nf = 0; nf < 2; ++nf) {
      int row = 32 * qc + 16 * nf + cl;
      int colb = 32 * qr + 16 * mf + 4 * g;
      int ph = row * 64 + ((((colb >> 3) ^ (row & 7))) << 3) + (colb & 7);
      float v0 = a[mf][nf][0], v1 = a[mf][nf][1], v2 = a[mf][nf][2], v3 = a[mf][nf][3];
      f16x2 h01 = cvt_pk(v0, v1);
      f16x2 h23 = cvt_pk(v2, v3);
      f16x2 l01 = cvt_pk(v0 - (float)h01[0], v1 - (float)h01[1]);
      f16x2 l23 = cvt_pk(v2 - (float)h23[0], v3 - (float)h23[1]);
      union { f16x2 f[2]; uint2 u; } H, L;
      H.f[0] = h01; H.f[1] = h23; L.f[0] = l01; L.f[1] = l23;
      *reinterpret_cast<uint2*>(D + ph) = H.u;
      *reinterpret_cast<uint2*>(D + LOFF + ph) = L.u;
    }
}

// store C^T to global fp32
__device__ __forceinline__ void st_f32g(float* __restrict__ dst, const f32x4 (&a)[2][2],
                                        float sc) {
  int t = threadIdx.x, lane = t & 63, cl = lane & 15, g = lane >> 4;
  int wid = t >> 6, qr = wid >> 1, qc = wid & 1;
#pragma unroll
  for (int mf = 0; mf < 2; ++mf)
#pragma unroll
    for (int nf = 0; nf < 2; ++nf) {
      int row = 32 * qc + 16 * nf + cl;
      int colb = 32 * qr + 16 * mf + 4 * g;
      *reinterpret_cast<float4*>(dst + row * 64 + colb) =
          make_float4(a[mf][nf][0] * sc, a[mf][nf][1] * sc, a[mf][nf][2] * sc,
                      a[mf][nf][3] * sc);
    }
}

__device__ __forceinline__ float block_reduce_sum(float v, float* red) {
  int t = threadIdx.x;
  red[t] = v;
  __syncthreads();
#pragma unroll
  for (int sft = 128; sft >= 1; sft >>= 1) {
    if (t < sft) red[t] += red[t + sft];
    __syncthreads();
  }
  float r = red[0];
  __syncthreads();
  return r;
}

// ---------------- kernels ----------------

__global__ void k_mean_part(const float* __restrict__ x, float* __restrict__ part) {
  float4 s[4];
#pragma unroll
  for (int q = 0; q < 4; ++q) s[q] = make_float4(0.f, 0.f, 0.f, 0.f);
  int base = blockIdx.x * 16;
  for (int b = 0; b < 16; ++b) {
    const float4* x4 = reinterpret_cast<const float4*>(x + (size_t)(base + b) * 4096);
#pragma unroll
    for (int q = 0; q < 4; ++q) {
      float4 v = x4[threadIdx.x + (q << 8)];
      s[q].x += v.x; s[q].y += v.y; s[q].z += v.z; s[q].w += v.w;
    }
  }
  float4* p4 = reinterpret_cast<float4*>(part + (size_t)blockIdx.x * 4096);
#pragma unroll
  for (int q = 0; q < 4; ++q) p4[threadIdx.x + (q << 8)] = s[q];
}

// 256 blocks; block handles 16 outputs, 16 p-groups of 32 partials each
__global__ void k_reduce(const float* __restrict__ part, float scale,
                         float* __restrict__ o) {
  __shared__ float red[256];
  int t = threadIdx.x;
  int j = blockIdx.x * 16 + (t & 15);
  int pg = t >> 4;
  float s = 0.f;
#pragma unroll 4
  for (int i = 0; i < 32; ++i) s += part[(size_t)(pg + 16 * i) * 4096 + j];
  red[t] = s;
  __syncthreads();
#pragma unroll
  for (int off = 128; off >= 16; off >>= 1) {
    if (t < off) red[t] += red[t + off];
    __syncthreads();
  }
  if (t < 16) o[blockIdx.x * 16 + t] = red[t] * scale;
}

// Block 0: s,si from mean0 via near-identity series + 1 NS polish.
// Block 1: gsq = sqrtm(G) via Chebyshev-PS (s=4, deg 31) on [0.45, 7].
__global__ __launch_bounds__(256) void k_prep1(const float* __restrict__ mean0,
                                               const float* __restrict__ G,
                                               float* __restrict__ s_out,
                                               float* __restrict__ si_out,
                                               float* __restrict__ gsq_out, ChebS cs) {
  __shared__ __align__(16) half_t P0[SLOTH], P1[SLOTH], P2[SLOTH];
  __shared__ float red[256];
  int t = threadIdx.x, lane = t & 63, cl = lane & 15, g = lane >> 4;
  int wid = t >> 6, qr = wid >> 1, qc = wid & 1;
  float qd = (qr == qc) ? 1.f : 0.f;
  f32x4 dmv;
#pragma unroll
  for (int r = 0; r < 4; ++r) dmv[r] = (cl == 4 * g + r) ? 1.f : 0.f;
  int row = t >> 2, k0 = (t & 3) << 4;
  f32x4 acc[2][2];

  if (blockIdx.x == 0) {
    float e[16];
    load16g(mean0, e);
    float tl = ((t & 3) == (row >> 4)) ? e[row & 15] : 0.f;
    float m = block_reduce_sum(tl, red) * (1.f / 64.f);
    float de[16];
#pragma unroll
    for (int j = 0; j < 16; ++j) de[j] = e[j] / m - ((k0 + j == row) ? 1.f : 0.f);
    e2slot_d(de, P0, 1.f, 0.f);
    __syncthreads();
    gemm_sA_sB(P0, P0, acc);                 // D2
    st_nat(P1, acc);
    __syncthreads();
    float d2e[16];
    slot2e(P1, d2e);
    float we[16];
#pragma unroll
    for (int j = 0; j < 16; ++j) {
      float dg = (k0 + j == row) ? 1.f : 0.f;
      we[j] = -0.125f * dg + 0.0625f * de[j] - 0.0390625f * d2e[j];
    }
    e2slot_d(we, P2, 1.f, 0.f);
    __syncthreads();
    gemm_sA_sB(P1, P2, acc);                 // D2*W
    st_nat(P0, acc);
    __syncthreads();
    float qe[16];
    slot2e(P0, qe);
    float ye[16], wz[16];
#pragma unroll
    for (int j = 0; j < 16; ++j) {
      float dg = (k0 + j == row) ? 1.f : 0.f;
      ye[j] = dg + 0.5f * de[j] + qe[j];
      wz[j] = 0.375f * dg - 0.3125f * de[j] + 0.2734375f * d2e[j];
    }
    e2slot_d(wz, P2, 1.f, 0.f);
    __syncthreads();
    gemm_sA_sB(P1, P2, acc);                 // D2*Wz
    st_nat(P0, acc);
    __syncthreads();
    float qz[16];
    slot2e(P0, qz);
    float ze[16];
#pragma unroll
    for (int j = 0; j < 16; ++j) {
      float dg = (k0 + j == row) ? 1.f : 0.f;
      ze[j] = dg - 0.5f * de[j] + qz[j];
    }
    e2slot_d(ye, P0, 1.f, 0.f);
    e2slot_d(ze, P1, 1.f, 0.f);
    __syncthreads();
    gemm_sA_sB(P1, P0, acc);                 // Z*Y
    f32x4 nmat[2][2];
#pragma unroll
    for (int mf = 0; mf < 2; ++mf)
#pragma unroll
      for (int nf = 0; nf < 2; ++nf) {
        nmat[mf][nf] = -0.5f * acc[mf][nf];
        if (mf == nf) nmat[mf][nf] += (1.5f * qd) * dmv;
      }
    st_nat(P2, nmat);
    __syncthreads();
    f32x4 aY[2][2], aZ[2][2];
    gemm_sA_sB(P0, P2, aY);                  // Y*N
    gemm_sA_sB(P2, P1, aZ);                  // N*Z
    float sm = sqrtf(m);
    st_f32g(s_out, aY, sm);
    st_f32g(si_out, aZ, 1.f / sm);
  } else {
    float e[16];
    load16g(G, e);
    e2slot_d(e, P0, cs.invh, cs.mhat * cs.invh);   // U
    __syncthreads();
    f32x4 t1c[2][2], t2c[2][2], t3c[2][2];
    ld_cfrags(P0, t1c);
    gemm_sA_sB(P0, P0, acc);
#pragma unroll
    for (int mf = 0; mf < 2; ++mf)
#pragma unroll
      for (int nf = 0; nf < 2; ++nf) {
        t2c[mf][nf] = 2.f * acc[mf][nf];
        if (mf == nf) t2c[mf][nf] -= qd * dmv;
      }
    st_nat(P1, t2c);
    __syncthreads();
    gemm_sA_sB(P0, P1, acc);
#pragma unroll
    for (int mf = 0; mf < 2; ++mf)
#pragma unroll
      for (int nf = 0; nf < 2; ++nf) t3c[mf][nf] = 2.f * acc[mf][nf] - t1c[mf][nf];
    st_nat(P2, t3c);
    __syncthreads();
    gemm_sA_sB(P0, P2, acc);                 // U*T3
    {
      f32x4 vv[2][2];
#pragma unroll
      for (int mf = 0; mf < 2; ++mf)
#pragma unroll
        for (int nf = 0; nf < 2; ++nf) vv[mf][nf] = 2.f * acc[mf][nf] - t2c[mf][nf];
      st_nat(P1, vv);                        // V = T4
    }
    __syncthreads();
    f32x4 bcur[2][2], bprev[2][2];
#pragma unroll
    for (int mf = 0; mf < 2; ++mf)
#pragma unroll
      for (int nf = 0; nf < 2; ++nf) {
        f32x4 q = (mf == nf) ? (qd * cs.g[7][0]) * dmv : (f32x4){0.f, 0.f, 0.f, 0.f};
        q += cs.g[7][1] * t1c[mf][nf];
        q += cs.g[7][2] * t2c[mf][nf];
        q += cs.g[7][3] * t3c[mf][nf];
        bcur[mf][nf] = q;
        bprev[mf][nf] = (f32x4){0.f, 0.f, 0.f, 0.f};
      }
#pragma unroll
    for (int it = 0; it < 6; ++it) {
      half_t* sl = (it & 1) ? P2 : P0;
      st_nat(sl, bcur);
      __syncthreads();
      gemm_sA_sB(P1, sl, acc);               // V*b
      int J = 6 - it;
#pragma unroll
      for (int mf = 0; mf < 2; ++mf)
#pragma unroll
        for (int nf = 0; nf < 2; ++nf) {
          f32x4 q = (mf == nf) ? (qd * cs.g[J][0]) * dmv : (f32x4){0.f, 0.f, 0.f, 0.f};
          q += cs.g[J][1] * t1c[mf][nf];
          q += cs.g[J][2] * t2c[mf][nf];
          q += cs.g[J][3] * t3c[mf][nf];
          f32x4 bn = q + 2.f * acc[mf][nf] - bprev[mf][nf];
          bprev[mf][nf] = bcur[mf][nf];
          bcur[mf][nf] = bn;
        }
    }
    st_nat(P0, bcur);
    __syncthreads();
    gemm_sA_sB(P1, P0, acc);
    f32x4 res[2][2];
#pragma unroll
    for (int mf = 0; mf < 2; ++mf)
#pragma unroll
      for (int nf = 0; nf < 2; ++nf) {
        f32x4 q = (mf == nf) ? (qd * cs.g[0][0]) * dmv : (f32x4){0.f, 0.f, 0.f, 0.f};
        q += cs.g[0][1] * t1c[mf][nf];
        q += cs.g[0][2] * t2c[mf][nf];
        q += cs.g[0][3] * t3c[mf][nf];
        res[mf][nf] = q + acc[mf][nf] - bprev[mf][nf];
      }
    st_f32g(gsq_out, res, 1.f);
  }
}

__device__ __forceinline__ void qevalL(const ChebL& ca, int J, const f32x4 (&tt)[7][2][2],
                                       const f32x4& dmv, float qd, f32x4 (&o)[2][2]) {
  float g0 = qd * ca.g[J][0];
#pragma unroll
  for (int mf = 0; mf < 2; ++mf)
#pragma unroll
    for (int nf = 0; nf < 2; ++nf) {
      f32x4 q = (mf == nf) ? g0 * dmv : (f32x4){0.f, 0.f, 0.f, 0.f};
#pragma unroll
      for (int tx = 1; tx < 8; ++tx) q += ca.g[J][tx] * tt[tx - 1][mf][nf];
      o[mf][nf] = q;
    }
}

// Heavy kernel: per matrix M = si*x*si; logm via Chebyshev-PS (s=8, deg 63);
// accumulate sum over 16 matrices -> part[blk][4096]. 512 blocks x 256 thr.
__global__ __launch_bounds__(256, 2) void k_logm_sum(const float* __restrict__ x,
                                                     const float* __restrict__ si,
                                                     float* __restrict__ part,
                                                     ChebL ca) {
  __shared__ __align__(16) half_t P0[SLOTH], P1[SLOTH], P2[SLOTH];   // 48 KB
  int t = threadIdx.x, lane = t & 63, cl = lane & 15, g = lane >> 4;
  int wid = t >> 6, qr = wid >> 1, qc = wid & 1;
  float qd = (qr == qc) ? 1.f : 0.f;
  f32x4 dmv;
#pragma unroll
  for (int r = 0; r < 4; ++r) dmv[r] = (cl == 4 * g + r) ? 1.f : 0.f;

  Frag8 SB = ld_rowfrags_g(si, qc);          // si B-frags, fixed for all matrices

  f32x4 sum[2][2];
  ZACC(sum);
  f32x4 tt[7][2][2], acc[2][2];

#pragma unroll 1
  for (int mm = 0; mm < 16; ++mm) {
    const float* xb = x + ((size_t)blockIdx.x * 16 + mm) * 4096;
    g2slot(xb, P0);
    __syncthreads();

    gemm_sA_rB(P0, SB, acc);                 // x * si^T
    st_nat(P1, acc);                         // P1 = si x
    __syncthreads();

    gemm_sA_rB(P1, SB, acc);                 // (si x) * si^T = M
    {
      float md = qd * ca.mhat;
#pragma unroll
      for (int mf = 0; mf < 2; ++mf)
#pragma unroll
        for (int nf = 0; nf < 2; ++nf) {
          f32x4 v = acc[mf][nf];
          if (mf == nf) v -= md * dmv;
          tt[0][mf][nf] = v * ca.invh;       // T1 = U
        }
    }
    st_nat(P0, tt[0]);                       // P0 = U (x dead)
    __syncthreads();

    Frag8 AC = ld_rowfrags(P0, qr);          // U rows (A-side), reused 7x
    gemm_rA_sB(AC, P0, acc);                 // U*U
#pragma unroll
    for (int mf = 0; mf < 2; ++mf)
#pragma unroll
      for (int nf = 0; nf < 2; ++nf) {
        tt[1][mf][nf] = 2.f * acc[mf][nf];
        if (mf == nf) tt[1][mf][nf] -= qd * dmv;
      }
    st_nat(P1, tt[1]);
    __syncthreads();

    // T3..T7: read P1/P2 alternating, write the other
#pragma unroll
    for (int n = 3; n <= 7; ++n) {
      const half_t* rd = ((n - 3) & 1) ? P2 : P1;
      half_t* wr = ((n - 3) & 1) ? P1 : P2;
      gemm_rA_sB(AC, rd, acc);
#pragma unroll
      for (int mf = 0; mf < 2; ++mf)
#pragma unroll
        for (int nf = 0; nf < 2; ++nf)
          tt[n - 1][mf][nf] = 2.f * acc[mf][nf] - tt[n - 3][mf][nf];
      st_nat(wr, tt[n - 1]);
      __syncthreads();
    }
    // T7 is in P2. V = T8 = 2 U T7 - T6
    gemm_rA_sB(AC, P2, acc);
    {
      f32x4 vv[2][2];
#pragma unroll
      for (int mf = 0; mf < 2; ++mf)
#pragma unroll
        for (int nf = 0; nf < 2; ++nf) vv[mf][nf] = 2.f * acc[mf][nf] - tt[5][mf][nf];
      st_nat(P0, vv);                        // P0 = V
    }
    __syncthreads();
    AC = ld_rowfrags(P0, qr);                // V rows (A-side), reused 7x

    // Clenshaw over 8 blocks
    f32x4 bcur[2][2], bprev[2][2];
    qevalL(ca, 7, tt, dmv, qd, bcur);
    ZACC(bprev);
#pragma unroll
    for (int it = 0; it < 6; ++it) {
      half_t* sl = (it & 1) ? P2 : P1;
      st_nat(sl, bcur);
      __syncthreads();
      gemm_rA_sB(AC, sl, acc);               // V*b
      f32x4 q[2][2];
      qevalL(ca, 6 - it, tt, dmv, qd, q);
#pragma unroll
      for (int mf = 0; mf < 2; ++mf)
#pragma unroll
        for (int nf = 0; nf < 2; ++nf) {
          f32x4 bn = q[mf][nf] + 2.f * acc[mf][nf] - bprev[mf][nf];
          bprev[mf][nf] = bcur[mf][nf];
          bcur[mf][nf] = bn;
        }
    }
    st_nat(P1, bcur);                        // b1 (last read slot was P2)
    __syncthreads();
    gemm_rA_sB(AC, P1, acc);                 // V*b1
    {
      f32x4 q0[2][2];
      qevalL(ca, 0, tt, dmv, qd, q0);
#pragma unroll
      for (int mf = 0; mf < 2; ++mf)
#pragma unroll
        for (int nf = 0; nf < 2; ++nf)
          sum[mf][nf] += q0[mf][nf] + acc[mf][nf] - bprev[mf][nf];
    }
  }
  st_f32g(part + (size_t)blockIdx.x * 4096, sum, 1.f);
}

// E=exp(gamma)*Taylor6(meanT-gamma*I); center=s*E*s; csi via series+1 NS polish;
// P stored row-major. One block.
__global__ __launch_bounds__(256) void k_prep2(const float* __restrict__ meanT,
                                               const float* __restrict__ s_m,
                                               const float* __restrict__ gsq,
                                               float* __restrict__ P_out) {
  __shared__ __align__(16) half_t S0[SLOTH], S1[SLOTH], S2[SLOTH], S3[SLOTH], S4[SLOTH];
  __shared__ float red[256];
  int t = threadIdx.x, lane = t & 63, cl = lane & 15, g = lane >> 4;
  int wid = t >> 6, qr = wid >> 1, qc = wid & 1;
  float qd = (qr == qc) ? 1.f : 0.f;
  f32x4 dmv;
#pragma unroll
  for (int r = 0; r < 4; ++r) dmv[r] = (cl == 4 * g + r) ? 1.f : 0.f;
  int row = t >> 2, k0 = (t & 3) << 4;
  f32x4 acc[2][2];

  float e[16];
  load16g(meanT, e);
  float tl = ((t & 3) == (row >> 4)) ? e[row & 15] : 0.f;
  float gama = block_reduce_sum(tl, red) * (1.f / 64.f);
  float de[16];
#pragma unroll
  for (int j = 0; j < 16; ++j) de[j] = e[j] - gama * ((k0 + j == row) ? 1.f : 0.f);
  e2slot_d(de, S0, 1.f, 0.f);
  __syncthreads();
  gemm_sA_sB(S0, S0, acc);                   // D2
  st_nat(S1, acc);
  __syncthreads();
  float d2e[16];
  slot2e(S1, d2e);
  gemm_sA_sB(S1, S0, acc);                   // D3
  st_nat(S2, acc);
  __syncthreads();
  float d3e[16];
  slot2e(S2, d3e);
  float be[16];
#pragma unroll
  for (int j = 0; j < 16; ++j)
    be[j] = (1.f / 24.f) * de[j] + (1.f / 120.f) * d2e[j] + (1.f / 720.f) * d3e[j];
  e2slot_d(be, S3, 1.f, 0.f);
  __syncthreads();
  gemm_sA_sB(S2, S3, acc);                   // D3*B
  st_nat(S4, acc);
  __syncthreads();
  float r4e[16];
  slot2e(S4, r4e);
  float ee[16];
#pragma unroll
  for (int j = 0; j < 16; ++j) {
    float dg = (k0 + j == row) ? 1.f : 0.f;
    ee[j] = dg + de[j] + 0.5f * d2e[j] + (1.f / 6.f) * d3e[j] + r4e[j];
  }
  e2slot_d(ee, S0, 1.f, 0.f);                // S0 = E~ (unit scale)
  {
    float es[16];
    load16g(s_m, es);
    e2slot_d(es, S1, 1.f, 0.f);              // S1 = s
  }
  __syncthreads();
  gemm_sA_sB(S0, S1, acc);                   // E~*s
  st_nat(S2, acc);                           // S2 = s*E~
  __syncthreads();
  gemm_sA_sB(S2, S1, acc);                   // s*E~*s = center~
  tl = 0.f;
#pragma unroll
  for (int mf = 0; mf < 2; ++mf)
#pragma unroll
    for (int r = 0; r < 4; ++r) tl += dmv[r] * acc[mf][mf][r];
  tl *= qd;
  float mc = block_reduce_sum(tl, red) * (1.f / 64.f);
  f32x4 dcf[2][2];
#pragma unroll
  for (int mf = 0; mf < 2; ++mf)
#pragma unroll
    for (int nf = 0; nf < 2; ++nf) {
      dcf[mf][nf] = acc[mf][nf] * (1.f / mc);
      if (mf == nf) dcf[mf][nf] -= qd * dmv;
    }
  st_nat(S0, dcf);                           // S0 = Dc
  __syncthreads();
  gemm_sA_sB(S0, S0, acc);                   // Dc^2
  st_nat(S1, acc);
  {
    f32x4 wzf[2][2];
#pragma unroll
    for (int mf = 0; mf < 2; ++mf)
#pragma unroll
      for (int nf = 0; nf < 2; ++nf) {
        wzf[mf][nf] = -0.3125f * dcf[mf][nf];
        if (mf == nf) wzf[mf][nf] += (0.375f * qd) * dmv;
      }
    st_nat(S3, wzf);
  }
  __syncthreads();
  gemm_sA_sB(S1, S3, acc);                   // Dc^2 * Wz
  {
    f32x4 z0[2][2];
#pragma unroll
    for (int mf = 0; mf < 2; ++mf)
#pragma unroll
      for (int nf = 0; nf < 2; ++nf) {
        z0[mf][nf] = acc[mf][nf] - 0.5f * dcf[mf][nf];
        if (mf == nf) z0[mf][nf] += qd * dmv;
      }
    st_nat(S2, z0);                          // S2 = Z0
  }
  __syncthreads();
  f32x4 accw[2][2];
  gemm_sA_sB(S2, S2, accw);                  // W = Z^2
  st_nat(S3, accw);
  __syncthreads();
  gemm_sA_sB(S0, S3, acc);                   // Dc*W
  {
    f32x4 nmat[2][2];
#pragma unroll
    for (int mf = 0; mf < 2; ++mf)
#pragma unroll
      for (int nf = 0; nf < 2; ++nf) {
        nmat[mf][nf] = -0.5f * (accw[mf][nf] + acc[mf][nf]);
        if (mf == nf) nmat[mf][nf] += (1.5f * qd) * dmv;
      }
    st_nat(S1, nmat);
  }
  __syncthreads();
  gemm_sA_sB(S2, S1, acc);                   // Znew = Z*N
  st_nat(S0, acc);
  __syncthreads();
  {
    float eg[16];
    load16g(gsq, eg);
    e2slot_d(eg, S1, 1.f, 0.f);
  }
  __syncthreads();
  gemm_sA_sB(S0, S1, acc);                   // Znew*gsq  -> transpose-store = P
  st_f32g(P_out, acc, 1.f / sqrtf(mc * expf(gama)));
}

// out_b = P*x_b*P^T. 2048 blocks x 4 matrices. Coalesced epilogue via f32 LDS.
__global__ __launch_bounds__(256) void k_out(const float* __restrict__ x,
                                             const float* __restrict__ P,
                                             float* __restrict__ out) {
  __shared__ __align__(16) half_t SX[SLOTH], ST[SLOTH];
  __shared__ __align__(16) float SF[64 * 68];
  int t = threadIdx.x, lane = t & 63, cl = lane & 15, g = lane >> 4;
  int wid = t >> 6, qr = wid >> 1, qc = wid & 1;
  int row = t >> 2, k0 = (t & 3) << 4;
  Frag8 PB = ld_rowfrags_g(P, qc);           // P rows (B-side), fixed
  f32x4 acc[2][2];
#pragma unroll 1
  for (int mm = 0; mm < 4; ++mm) {
    size_t b = (size_t)blockIdx.x * 4 + mm;
    g2slot(x + b * 4096, SX);
    __syncthreads();
    gemm_sA_rB(SX, PB, acc);                 // x * P^T
    st_nat(ST, acc);                         // ST = P x
    __syncthreads();
    gemm_sA_rB(ST, PB, acc);                 // (P x) * P^T
#pragma unroll
    for (int mf = 0; mf < 2; ++mf)
#pragma unroll
      for (int nf = 0; nf < 2; ++nf) {
        int rr = 32 * qc + 16 * nf + cl;
        int colb = 32 * qr + 16 * mf + 4 * g;
        *reinterpret_cast<float4*>(SF + rr * 68 + colb) =
            make_float4(acc[mf][nf][0], acc[mf][nf][1], acc[mf][nf][2], acc[mf][nf][3]);
      }
    __syncthreads();
    float* ob = out + b * 4096;
#pragma unroll
    for (int q = 0; q < 4; ++q)
      *reinterpret_cast<float4*>(ob + row * 64 + k0 + 4 * q) =
          *reinterpret_cast<const float4*>(SF + row * 68 + k0 + 4 * q);
    __syncthreads();
  }
}

// ---------------- host ----------------

extern "C" void kernel_launch(void* const* d_in, const int* in_sizes, int n_in,
                              void* d_out, int out_size, void* d_ws, size_t ws_size,
                              hipStream_t stream) {
  (void)in_sizes; (void)n_in; (void)out_size; (void)ws_size;
  const float* x = (const float*)d_in[0];   // [8192,64,64]
  const float* G = (const float*)d_in[1];   // [64,64]
  float* out = (float*)d_out;
  float* wsf = (float*)d_ws;

  float* part  = out;                       // 512*4096 floats (overwritten by k_out)
  float* mean0 = wsf;
  float* s_m   = wsf + 4096;
  float* si_m  = wsf + 8192;
  float* gsq   = wsf + 12288;
  float* meanT = wsf + 16384;
  float* Pm    = wsf + 20480;

  // log coefficients on [0.05, 5.5], degree 63, PS-folded (s=8, r=8)
  ChebL caL;
  {
    const double a = 0.05, b = 5.5;
    const double m = 0.5 * (a + b), h = 0.5 * (b - a);
    const double r = h / m;
    const double z = (1.0 - sqrt(1.0 - r * r)) / r;
    double c[64];
    c[0] = log(m) - log(1.0 + z * z);
    double zk = z;
    for (int k = 1; k < 64; ++k) {
      c[k] = 2.0 * ((k & 1) ? 1.0 : -1.0) * zk / (double)k;
      zk *= z;
    }
    double gg[8][8];
    for (int j = 0; j < 8; ++j) for (int i = 0; i < 8; ++i) gg[j][i] = 0.0;
    for (int j = 7; j >= 1; --j) {
      for (int i = 1; i <= 7; ++i) {
        gg[j][i] = 2.0 * c[j * 8 + i];
        c[(j - 1) * 8 + (8 - i)] -= c[j * 8 + i];
      }
      gg[j][0] = c[j * 8];
    }
    for (int i = 0; i < 8; ++i) gg[0][i] = c[i];
    for (int j = 0; j < 8; ++j)
      for (int i = 0; i < 8; ++i) caL.g[j][i] = (float)gg[j][i];
    caL.mhat = (float)m;
    caL.invh = (float)(1.0 / h);
  }

  // sqrt coefficients on [0.45, 7.0], degree 31, PS-folded (s=4, r=8)
  ChebS caS;
  {
    const double msq = 0.5 * (0.45 + 7.0), hsq = 0.5 * (7.0 - 0.45);
    const int NN = 128;
    double cc[32];
    for (int k = 0; k < 32; ++k) {
      double sAcc = 0.0;
      for (int j = 0; j < NN; ++j) {
        double th = M_PI * (j + 0.5) / NN;
        sAcc += sqrt(msq + hsq * cos(th)) * cos(k * th);
      }
      cc[k] = 2.0 * sAcc / NN;
    }
    cc[0] *= 0.5;
    double g4[8][4];
    for (int j = 0; j < 8; ++j) for (int i = 0; i < 4; ++i) g4[j][i] = 0.0;
    for (int j = 7; j >= 1; --j) {
      for (int i = 1; i <= 3; ++i) {
        g4[j][i] = 2.0 * cc[4 * j + i];
        cc[4 * (j - 1) + (4 - i)] -= cc[4 * j + i];
      }
      g4[j][0] = cc[4 * j];
    }
    for (int i = 0; i < 4; ++i) g4[0][i] = cc[i];
    for (int j = 0; j < 8; ++j)
      for (int i = 0; i < 4; ++i) caS.g[j][i] = (float)g4[j][i];
    caS.mhat = (float)msq;
    caS.invh = (float)(1.0 / hsq);
  }

  hipLaunchKernelGGL(k_mean_part, dim3(512), dim3(256), 0, stream, x, part);
  hipLaunchKernelGGL(k_reduce, dim3(256), dim3(256), 0, stream, part, 1.f / 8192.f, mean0);
  hipLaunchKernelGGL(k_prep1, dim3(2), dim3(256), 0, stream, mean0, G, s_m, si_m, gsq, caS);
  hipLaunchKernelGGL(k_logm_sum, dim3(512), dim3(256), 0, stream, x, si_m, part, caL);
  hipLaunchKernelGGL(k_reduce, dim3(256), dim3(256), 0, stream, part, 1.f / 8192.f, meanT);
  hipLaunchKernelGGL(k_prep2, dim3(1), dim3(256), 0, stream, meanT, s_m, gsq, Pm);
  hipLaunchKernelGGL(k_out, dim3(2048), dim3(256), 0, stream, x, Pm, out);
}